// Round 6
// baseline (41.780 us; speedup 1.0000x reference)
//
#include <hip/hip_runtime.h>

// B=8, X=Y=Z=128, f32. out = active * Lap(mu*active) / dx^2, periodic.
// Register-marching 2.5D: thread owns (y, z0..z0+3) column, marches x.
// TX=32 to cut x-halo: demand = 128MB*1.1875 + 64MB write.
#define NB 8
#define NX 128
#define NY 128
#define NZ 128

#define TY 16
#define TX 32
#define XC (NX / TX)     // 4
#define YT (NY / TY)     // 8
#define ROWS (TY + 2)    // 18

__global__ __launch_bounds__(512) void lap_march(
    const float* __restrict__ mu,
    const float* __restrict__ act,
    const float* __restrict__ dxp,
    float* __restrict__ out)
{
    __shared__ float buf[2][ROWS][NZ];   // 18432 B, double-buffered e-planes

    const int tid = threadIdx.x;         // 0..511
    const int bid = blockIdx.x;
    const int xc = bid & (XC - 1);
    const int yt = (bid >> 2) & (YT - 1);
    const int b  = bid >> 5;

    const int x0 = xc * TX;
    const int y0 = yt * TY;
    const int planeYZ = NY * NZ;         // 16384
    const int baseB = b * NX * planeYZ;

    const float dxv = dxp[0];
    const float inv = 1.0f / (dxv * dxv);

    const int r  = tid >> 5;             // 0..15 (y row within tile)
    const int zq = tid & 31;
    const int z0 = zq * 4;
    const int gy = y0 + r;

    float4 eP, eC, eN, aC, aN;

    auto ldE = [&](int gx, float4* ev, float4* av) {
        const int gIdx = baseB + gx * planeYZ + gy * NZ + z0;
        float4 m = *reinterpret_cast<const float4*>(mu + gIdx);
        float4 a = *reinterpret_cast<const float4*>(act + gIdx);
        *av = a;
        *ev = make_float4(m.x * a.x, m.y * a.y, m.z * a.z, m.w * a.w);
    };

    auto ldHalo = [&](int gx, int slot) {
        // 2 y-halo rows x 32 z-quads, done by wave 0
        if (tid < 64) {
            const int hr = tid >> 5;               // 0: y-1, 1: y+TY
            const int hz = (tid & 31) * 4;
            const int hy = hr ? ((y0 + TY) & (NY - 1)) : ((y0 - 1) & (NY - 1));
            const int gIdx = baseB + gx * planeYZ + hy * NZ + hz;
            float4 m = *reinterpret_cast<const float4*>(mu + gIdx);
            float4 a = *reinterpret_cast<const float4*>(act + gIdx);
            *reinterpret_cast<float4*>(&buf[slot][hr ? TY + 1 : 0][hz]) =
                make_float4(m.x * a.x, m.y * a.y, m.z * a.z, m.w * a.w);
        }
    };

    // prologue: eP = plane x0-1 (regs only, no y-halo), eC/buf[0] = plane x0
    {
        float4 dummy;
        ldE((x0 - 1) & (NX - 1), &eP, &dummy);
        ldE(x0, &eC, &aC);
        *reinterpret_cast<float4*>(&buf[0][r + 1][z0]) = eC;
        ldHalo(x0, 0);
    }
    __syncthreads();

    for (int i = 0; i < TX; ++i) {
        // load plane x0+i+1 -> eN regs; to LDS buf[(i+1)&1] unless it's the
        // reg-only exit halo plane (i == TX-1)
        const int gxn = (x0 + i + 1) & (NX - 1);
        ldE(gxn, &eN, &aN);
        if (i < TX - 1) {
            *reinterpret_cast<float4*>(&buf[(i + 1) & 1][r + 1][z0]) = eN;
            ldHalo(gxn, (i + 1) & 1);
        }

        // compute plane x0+i from regs + buf[i&1]
        const int s = i & 1;
        float4 eym = *reinterpret_cast<const float4*>(&buf[s][r][z0]);
        float4 eyp = *reinterpret_cast<const float4*>(&buf[s][r + 2][z0]);
        float ezm = __shfl(eC.w, (zq + 31) & 31, 32);  // z0-1 (periodic in 32-group)
        float ezp = __shfl(eC.x, (zq + 1) & 31, 32);   // z0+4

        float4 o;
        o.x = (eP.x + eN.x + eym.x + eyp.x + ezm  + eC.y - 6.0f * eC.x) * inv * aC.x;
        o.y = (eP.y + eN.y + eym.y + eyp.y + eC.x + eC.z - 6.0f * eC.y) * inv * aC.y;
        o.z = (eP.z + eN.z + eym.z + eyp.z + eC.y + eC.w - 6.0f * eC.z) * inv * aC.z;
        o.w = (eP.w + eN.w + eym.w + eyp.w + eC.z + ezp  - 6.0f * eC.w) * inv * aC.w;

        const int gIdx = baseB + (x0 + i) * planeYZ + gy * NZ + z0;
        *reinterpret_cast<float4*>(out + gIdx) = o;

        eP = eC; eC = eN; aC = aN;
        __syncthreads();   // one barrier per plane (protects both buffers)
    }
}

extern "C" void kernel_launch(void* const* d_in, const int* in_sizes, int n_in,
                              void* d_out, int out_size, void* d_ws, size_t ws_size,
                              hipStream_t stream) {
    const float* mu  = (const float*)d_in[0];
    const float* act = (const float*)d_in[1];
    const float* dx  = (const float*)d_in[2];
    float* out = (float*)d_out;

    const int grid = NB * YT * XC;   // 256 blocks -> 1 block/CU
    lap_march<<<grid, 512, 0, stream>>>(mu, act, dx, out);
}

// Round 7
// 35.951 us; speedup vs baseline: 1.1621x; 1.1621x over previous
//
#include <hip/hip_runtime.h>

// B=8, X=Y=Z=128, f32. out = active * Lap(mu*active) / dx^2, periodic.
// 2.5D register march + 2-deep pipeline. 1024-thr block: TY=32 halves y-halo.
// Demand model: (128MB * (1 + 2/TY + 2/TX) + 64MB) / 6.3 TB/s, needs >=16 waves/CU.
#define NB 8
#define NX 128
#define NY 128
#define NZ 128

#define TY 32
#define TX 16
#define XC (NX / TX)     // 8
#define YT (NY / TY)     // 4
#define ROWS (TY + 2)    // 34

#define EMUL(e, m, a) \
    e.x = m.x * a.x; e.y = m.y * a.y; e.z = m.z * a.z; e.w = m.w * a.w;

__global__ __launch_bounds__(1024) void lap_pipe(
    const float* __restrict__ mu,
    const float* __restrict__ act,
    const float* __restrict__ dxp,
    float* __restrict__ out)
{
    __shared__ float buf[2][ROWS][NZ];   // 34816 B

    const int tid = threadIdx.x;         // 0..1023
    const int bid = blockIdx.x;
    const int xc = bid & (XC - 1);       // bid%8 -> y-neighbor blocks share XCD
    const int yt = (bid >> 3) & (YT - 1);
    const int b  = bid >> 5;

    const int x0 = xc * TX;
    const int y0 = yt * TY;
    const int planeYZ = NY * NZ;         // 16384
    const int baseB = b * NX * planeYZ;

    const float dxv = dxp[0];
    const float inv = 1.0f / (dxv * dxv);

    const int r  = tid >> 5;             // 0..31
    const int zq = tid & 31;
    const int z0 = zq * 4;
    const int gy = y0 + r;
    const int rowOff = gy * NZ + z0;

    // y-halo duty: first 64 threads -> 2 halo rows x 32 z-quads
    const int hr   = tid >> 5;                       // 0 or 1 (valid tid<64)
    const int hy   = hr ? ((y0 + TY) & (NY - 1)) : ((y0 - 1) & (NY - 1));
    const int hRow = hr ? (TY + 1) : 0;
    const int hOff = hy * NZ + z0;

    float4 eP, eC, aC;        // products planes i-1, i; act plane i
    float4 mN, aN;            // raw mu/act plane i+1 (arrived)
    float4 mNN, aNN;          // raw plane i+2 (in flight)
    float4 hm, ha, hmNN, haNN;

    auto ld = [&](int gx, int off, float4* m, float4* a) {
        const int gIdx = baseB + gx * planeYZ + off;
        *m = *reinterpret_cast<const float4*>(mu + gIdx);
        *a = *reinterpret_cast<const float4*>(act + gIdx);
    };

    // ---- prologue ----
    {
        float4 m0, a0;
        ld((x0 - 1) & (NX - 1), rowOff, &m0, &a0);   // plane -1 (regs only)
        EMUL(eP, m0, a0);
        ld(x0, rowOff, &m0, &aC);                    // plane 0
        EMUL(eC, m0, aC);
        *reinterpret_cast<float4*>(&buf[0][r + 1][z0]) = eC;
        if (tid < 64) {
            float4 m1, a1, e1;
            ld(x0, hOff, &m1, &a1);
            EMUL(e1, m1, a1);
            *reinterpret_cast<float4*>(&buf[0][hRow][z0]) = e1;
        }
        ld((x0 + 1) & (NX - 1), rowOff, &mN, &aN);   // plane 1 raw
        if (tid < 64) ld((x0 + 1) & (NX - 1), hOff, &hm, &ha);
        __syncthreads();
    }

    for (int i = 0; i < TX; ++i) {
        // 1) issue loads for plane i+2 (consumed next iter)
        if (i < TX - 1) {
            const int gx2 = (x0 + i + 2) & (NX - 1);
            ld(gx2, rowOff, &mNN, &aNN);
            if (tid < 64) ld(gx2, hOff, &hmNN, &haNN);
        }

        // 2) plane i+1: product + LDS publish (mN/aN arrived one iter ago)
        float4 eN;
        EMUL(eN, mN, aN);
        if (i < TX - 1) {
            *reinterpret_cast<float4*>(&buf[(i + 1) & 1][r + 1][z0]) = eN;
            if (tid < 64) {
                float4 he;
                EMUL(he, hm, ha);
                *reinterpret_cast<float4*>(&buf[(i + 1) & 1][hRow][z0]) = he;
            }
        }

        // 3) compute plane i
        const int s = i & 1;
        float4 eym = *reinterpret_cast<const float4*>(&buf[s][r][z0]);
        float4 eyp = *reinterpret_cast<const float4*>(&buf[s][r + 2][z0]);
        float ezm = __shfl(eC.w, (zq + 31) & 31, 32);
        float ezp = __shfl(eC.x, (zq + 1) & 31, 32);

        float4 o;
        o.x = (eP.x + eN.x + eym.x + eyp.x + ezm  + eC.y - 6.0f * eC.x) * inv * aC.x;
        o.y = (eP.y + eN.y + eym.y + eyp.y + eC.x + eC.z - 6.0f * eC.y) * inv * aC.y;
        o.z = (eP.z + eN.z + eym.z + eyp.z + eC.y + eC.w - 6.0f * eC.z) * inv * aC.z;
        o.w = (eP.w + eN.w + eym.w + eyp.w + eC.z + ezp  - 6.0f * eC.w) * inv * aC.w;

        const int gIdx = baseB + (x0 + i) * planeYZ + rowOff;
        *reinterpret_cast<float4*>(out + gIdx) = o;

        // 4) rotate pipeline state
        eP = eC; eC = eN; aC = aN;
        mN = mNN; aN = aNN; hm = hmNN; ha = haNN;

        __syncthreads();   // one barrier per plane
    }
}

extern "C" void kernel_launch(void* const* d_in, const int* in_sizes, int n_in,
                              void* d_out, int out_size, void* d_ws, size_t ws_size,
                              hipStream_t stream) {
    const float* mu  = (const float*)d_in[0];
    const float* act = (const float*)d_in[1];
    const float* dx  = (const float*)d_in[2];
    float* out = (float*)d_out;

    const int grid = NB * YT * XC;   // 256 blocks, 1024 threads each
    lap_pipe<<<grid, 1024, 0, stream>>>(mu, act, dx, out);
}

// Round 8
// 33.574 us; speedup vs baseline: 1.2444x; 1.0708x over previous
//
#include <hip/hip_runtime.h>

// B=8, X=Y=Z=128, f32. out = active * Lap(mu*active) / dx^2, periodic.
// 2.5D register march, 2-deep pipeline, XCD-partitioned by batch sample
// (bid = (xc*4+yt)*8 + b -> XCD=b owns one full sample, halo rings closed
// intra-XCD) + pincer x-march (even xc down, odd xc up) so every x-halo
// reuse pair is same-plane same-iteration -> L2-hit instead of L3/fabric.
#define NB 8
#define NX 128
#define NY 128
#define NZ 128

#define TY 32
#define TX 16
#define XC (NX / TX)     // 8
#define YT (NY / TY)     // 4
#define ROWS (TY + 2)    // 34

typedef float f4v __attribute__((ext_vector_type(4)));

#define EMUL(e, m, a) \
    e.x = m.x * a.x; e.y = m.y * a.y; e.z = m.z * a.z; e.w = m.w * a.w;

__global__ __launch_bounds__(1024) void lap_pincer(
    const float* __restrict__ mu,
    const float* __restrict__ act,
    const float* __restrict__ dxp,
    float* __restrict__ out)
{
    __shared__ float buf[2][ROWS][NZ];   // 34816 B

    const int tid = threadIdx.x;         // 0..1023
    const int bid = blockIdx.x;
    const int b  = bid & 7;              // XCD index (round-robin bid%8)
    const int yt = (bid >> 3) & 3;
    const int xc = bid >> 5;

    const int x0 = xc * TX;
    const int y0 = yt * TY;
    const int fwd  = xc & 1;             // odd xc: up; even xc: down
    const int start = fwd ? x0 : x0 + TX - 1;
    const int step  = fwd ? 1 : -1;

    const int planeYZ = NY * NZ;         // 16384
    const int baseB = b * NX * planeYZ;

    const float dxv = dxp[0];
    const float inv = 1.0f / (dxv * dxv);

    const int r  = tid >> 5;             // 0..31
    const int zq = tid & 31;
    const int z0 = zq * 4;
    const int gy = y0 + r;
    const int rowOff = gy * NZ + z0;

    // y-halo duty: first 64 threads -> 2 halo rows x 32 z-quads
    const int hr   = tid >> 5;                       // 0 or 1 (valid tid<64)
    const int hy   = hr ? ((y0 + TY) & (NY - 1)) : ((y0 - 1) & (NY - 1));
    const int hRow = hr ? (TY + 1) : 0;
    const int hOff = hy * NZ + z0;

    float4 eP, eC, aC;        // products planes i-1, i; act plane i
    float4 mN, aN;            // raw mu/act plane i+1 (arrived)
    float4 mNN, aNN;          // raw plane i+2 (in flight)
    float4 hm, ha, hmNN, haNN;

    auto ld = [&](int gx, int off, float4* m, float4* a) {
        const int gIdx = baseB + gx * planeYZ + off;
        *m = *reinterpret_cast<const float4*>(mu + gIdx);
        *a = *reinterpret_cast<const float4*>(act + gIdx);
    };

    // ---- prologue ----
    {
        float4 m0, a0;
        ld((start - step) & (NX - 1), rowOff, &m0, &a0);  // behind plane (regs only)
        EMUL(eP, m0, a0);
        ld(start, rowOff, &m0, &aC);                      // plane 0
        EMUL(eC, m0, aC);
        *reinterpret_cast<float4*>(&buf[0][r + 1][z0]) = eC;
        if (tid < 64) {
            float4 m1, a1, e1;
            ld(start, hOff, &m1, &a1);
            EMUL(e1, m1, a1);
            *reinterpret_cast<float4*>(&buf[0][hRow][z0]) = e1;
        }
        ld(start + step, rowOff, &mN, &aN);               // plane 1 raw
        if (tid < 64) ld(start + step, hOff, &hm, &ha);
        __syncthreads();
    }

    for (int i = 0; i < TX; ++i) {
        // 1) issue loads for plane i+2 (consumed next iter)
        if (i < TX - 1) {
            const int gx2 = (start + (i + 2) * step) & (NX - 1);
            ld(gx2, rowOff, &mNN, &aNN);
            if (tid < 64) ld(gx2, hOff, &hmNN, &haNN);
        }

        // 2) plane i+1: product + LDS publish (mN/aN arrived one iter ago)
        float4 eN;
        EMUL(eN, mN, aN);
        if (i < TX - 1) {
            *reinterpret_cast<float4*>(&buf[(i + 1) & 1][r + 1][z0]) = eN;
            if (tid < 64) {
                float4 he;
                EMUL(he, hm, ha);
                *reinterpret_cast<float4*>(&buf[(i + 1) & 1][hRow][z0]) = he;
            }
        }

        // 3) compute plane i (x+- sum is symmetric -> direction-agnostic)
        const int s = i & 1;
        float4 eym = *reinterpret_cast<const float4*>(&buf[s][r][z0]);
        float4 eyp = *reinterpret_cast<const float4*>(&buf[s][r + 2][z0]);
        float ezm = __shfl(eC.w, (zq + 31) & 31, 32);
        float ezp = __shfl(eC.x, (zq + 1) & 31, 32);

        float4 o;
        o.x = (eP.x + eN.x + eym.x + eyp.x + ezm  + eC.y - 6.0f * eC.x) * inv * aC.x;
        o.y = (eP.y + eN.y + eym.y + eyp.y + eC.x + eC.z - 6.0f * eC.y) * inv * aC.y;
        o.z = (eP.z + eN.z + eym.z + eyp.z + eC.y + eC.w - 6.0f * eC.z) * inv * aC.z;
        o.w = (eP.w + eN.w + eym.w + eyp.w + eC.z + ezp  - 6.0f * eC.w) * inv * aC.w;

        const int gIdx = baseB + (start + i * step) * planeYZ + rowOff;
        f4v ov = {o.x, o.y, o.z, o.w};
        __builtin_nontemporal_store(ov, reinterpret_cast<f4v*>(out + gIdx));

        // 4) rotate pipeline state
        eP = eC; eC = eN; aC = aN;
        mN = mNN; aN = aNN; hm = hmNN; ha = haNN;

        __syncthreads();   // one barrier per plane
    }
}

extern "C" void kernel_launch(void* const* d_in, const int* in_sizes, int n_in,
                              void* d_out, int out_size, void* d_ws, size_t ws_size,
                              hipStream_t stream) {
    const float* mu  = (const float*)d_in[0];
    const float* act = (const float*)d_in[1];
    const float* dx  = (const float*)d_in[2];
    float* out = (float*)d_out;

    const int grid = NB * YT * XC;   // 256 blocks, 1024 threads each
    lap_pincer<<<grid, 1024, 0, stream>>>(mu, act, dx, out);
}